// Round 3
// baseline (601.564 us; speedup 1.0000x reference)
//
#include <hip/hip_runtime.h>
#include <cstdint>
#include <cstring>

typedef short short8 __attribute__((ext_vector_type(8)));
typedef float float4v __attribute__((ext_vector_type(4)));
typedef float float4g __attribute__((ext_vector_type(4)));
typedef unsigned short ushort4v __attribute__((ext_vector_type(4)));
typedef unsigned int uint2v __attribute__((ext_vector_type(2)));

typedef __attribute__((address_space(3))) unsigned int lds_uint;
typedef __attribute__((address_space(1))) const unsigned int glob_uint;

static __device__ __forceinline__ void async16(void* lds, const void* g) {
    __builtin_amdgcn_global_load_lds((glob_uint*)g, (lds_uint*)lds, 16, 0, 0);
}

static __device__ __forceinline__ float b2f(unsigned short u) {
    unsigned int x = ((unsigned int)u) << 16;
    float f;
    __builtin_memcpy(&f, &x, 4);
    return f;
}
static __device__ __forceinline__ unsigned short f2b(float f) {
    unsigned int x;
    __builtin_memcpy(&x, &f, 4);
    unsigned int r = (x + 0x7fffu + ((x >> 16) & 1u)) >> 16;
    return (unsigned short)r;
}

// ---------------- fp32 -> bf16 convert ----------------
__global__ __launch_bounds__(256) void k_f2b(const float* __restrict__ in,
                                             unsigned short* __restrict__ out, int n) {
    int i = (blockIdx.x * 256 + threadIdx.x) * 4;
    if (i >= n) return;
    float4g v = *(const float4g*)(in + i);
    ushort4v r;
    r.x = f2b(v.x); r.y = f2b(v.y); r.z = f2b(v.z); r.w = f2b(v.w);
    *(ushort4v*)(out + i) = r;
}

// ---------------- bf16 GEMM (m97 recipe): C[M,N] = A[M,K] @ W[N,K]^T ----------------
__global__ __launch_bounds__(256, 3)
void k_gemm_bt(const unsigned short* __restrict__ A, int lda,
               const unsigned short* __restrict__ W,
               void* __restrict__ C, int ldc,
               int N, int K, int c_fp32) {
    __shared__ __align__(16) unsigned short As[128 * 32];
    __shared__ __align__(16) unsigned short Ws[128 * 32];
    const int tid = threadIdx.x;
    const int m0 = blockIdx.y * 128, n0 = blockIdx.x * 128;
    const int wave = tid >> 6, lane = tid & 63;
    const int wm = (wave >> 1) * 64, wn = (wave & 1) * 64;
    const int lrow = lane & 15, quad = lane >> 4;
    const int srow = lane >> 2, spiece = lane & 3;

    float4v acc[4][4];
    float4v z = {0.f, 0.f, 0.f, 0.f};
#pragma unroll
    for (int i = 0; i < 4; i++)
#pragma unroll
        for (int j = 0; j < 4; j++) acc[i][j] = z;

    for (int k0 = 0; k0 < K; k0 += 32) {
#pragma unroll
        for (int ii = 0; ii < 2; ++ii) {
            int i = wave + ii * 4;
            int row = i * 16 + srow;
            async16(&As[i * 512], &A[(size_t)(m0 + row) * lda + k0 + spiece * 8]);
            int wr = n0 + row;
            if (wr > N - 1) wr = N - 1;
            async16(&Ws[i * 512], &W[(size_t)wr * K + k0 + spiece * 8]);
        }
        __syncthreads();
        short8 af[4], bfr[4];
#pragma unroll
        for (int i = 0; i < 4; i++)
            af[i] = *(const short8*)&As[(wm + i * 16 + lrow) * 32 + quad * 8];
#pragma unroll
        for (int i = 0; i < 4; i++)
            bfr[i] = *(const short8*)&Ws[(wn + i * 16 + lrow) * 32 + quad * 8];
#pragma unroll
        for (int i = 0; i < 4; i++)
#pragma unroll
            for (int j = 0; j < 4; j++)
                acc[i][j] = __builtin_amdgcn_mfma_f32_16x16x32_bf16(af[i], bfr[j], acc[i][j], 0, 0, 0);
        __syncthreads();
    }

    const int rbase = quad * 4;
#pragma unroll
    for (int i = 0; i < 4; i++) {
#pragma unroll
        for (int j = 0; j < 4; j++) {
            int col = n0 + wn + j * 16 + lrow;
            if (col >= N) continue;
#pragma unroll
            for (int r = 0; r < 4; r++) {
                int row = m0 + wm + i * 16 + rbase + r;
                float v = acc[i][j][r];
                if (c_fp32)
                    ((float*)C)[(size_t)row * ldc + col] = v;
                else
                    ((unsigned short*)C)[(size_t)row * ldc + col] = f2b(v);
            }
        }
    }
}

// ---------------- RMSNorm (vectorized short8, one row per block) ----------------
// blockDim.x = n/8 (192 for n=1536, 64 for n=512)
__global__ void k_rmsnorm8(unsigned short* __restrict__ x, const float* __restrict__ g,
                           int ld, int n) {
    int row = blockIdx.x;
    int tid = threadIdx.x;
    size_t base = (size_t)row * ld + tid * 8;
    short8 v8 = *(const short8*)(x + base);
    float vf[8];
    float ss = 0.f;
#pragma unroll
    for (int i = 0; i < 8; i++) {
        vf[i] = b2f((unsigned short)v8[i]);
        ss += vf[i] * vf[i];
    }
    for (int off = 32; off > 0; off >>= 1) ss += __shfl_xor(ss, off);
    __shared__ float wsum[4];
    int nw = blockDim.x >> 6;
    if (nw > 1) {
        int wave = tid >> 6, lane = tid & 63;
        if (lane == 0) wsum[wave] = ss;
        __syncthreads();
        ss = 0.f;
        for (int w = 0; w < nw; w++) ss += wsum[w];
    }
    float scale = rsqrtf(ss / (float)n + 1e-6f);
    short8 r8;
#pragma unroll
    for (int i = 0; i < 8; i++) r8[i] = (short)f2b(vf[i] * scale * g[tid * 8 + i]);
    *(short8*)(x + base) = r8;
}

// ---------------- RoPE on q_pe ----------------
__global__ __launch_bounds__(256) void k_rope_q(unsigned short* __restrict__ q) {
    int idx = blockIdx.x * 256 + threadIdx.x;  // 4096*16*32
    int d = idx & 31;
    int h = (idx >> 5) & 15;
    int t = idx >> 9;
    int s = t & 2047;
    size_t base = (size_t)t * 3072 + h * 192 + 128;
    float inv = powf(10000.0f, -(float)(2 * d) * (1.0f / 64.0f));
    float f = (float)s * inv;
    float c = cosf(f), sn = sinf(f);
    float x1 = b2f(q[base + d]), x2 = b2f(q[base + d + 32]);
    q[base + d] = f2b(x1 * c - x2 * sn);
    q[base + d + 32] = f2b(x2 * c + x1 * sn);
}

// ---------------- RoPE on k_pe ----------------
__global__ __launch_bounds__(256) void k_rope_k(unsigned short* __restrict__ ckv) {
    int idx = blockIdx.x * 256 + threadIdx.x;  // 4096*32
    int d = idx & 31;
    int t = idx >> 5;
    int s = t & 2047;
    size_t base = (size_t)t * 576 + 512;
    float inv = powf(10000.0f, -(float)(2 * d) * (1.0f / 64.0f));
    float f = (float)s * inv;
    float c = cosf(f), sn = sinf(f);
    float x1 = b2f(ckv[base + d]), x2 = b2f(ckv[base + d + 32]);
    ckv[base + d] = f2b(x1 * c - x2 * sn);
    ckv[base + d + 32] = f2b(x2 * c + x1 * sn);
}

// ---------------- V transpose: vt[bh][d][s] ----------------
__global__ __launch_bounds__(256) void k_transpose_v(const unsigned short* __restrict__ kv,
                                                     unsigned short* __restrict__ vt) {
    int bh = blockIdx.z;
    int b = bh >> 4, h = bh & 15;
    int s0 = blockIdx.x * 32, d0 = blockIdx.y * 32;
    __shared__ unsigned short t[32][33];
    int tx = threadIdx.x & 31, ty = threadIdx.x >> 5;
#pragma unroll
    for (int i = 0; i < 4; i++) {
        int s = s0 + ty + i * 8;
        t[ty + i * 8][tx] = kv[(size_t)(b * 2048 + s) * 4096 + h * 256 + 128 + d0 + tx];
    }
    __syncthreads();
#pragma unroll
    for (int i = 0; i < 4; i++) {
        int d = d0 + ty + i * 8;
        vt[((size_t)bh * 128 + d) * 2048 + s0 + tx] = t[tx][ty + i * 8];
    }
}

// ---------------- Flash attention v3 ----------------
// S^T = K·Q^T (softmax rows per-lane), dbuf K staging w/ 1 barrier/step,
// P row-major via ds_write_b64, V B-frags from global (L2).
// 512 blocks; lb<256: qt=lb>>5, else qt=15-((lb&255)>>5); bh=lb&31.
__global__ __launch_bounds__(256, 2)
void k_attn3(const unsigned short* __restrict__ q,     // [4096,3072] roped
             const unsigned short* __restrict__ kv,    // [4096,4096] k_nope|v
             const unsigned short* __restrict__ ckv,   // [4096,576] cols 512.. roped k_pe
             const unsigned short* __restrict__ vt,    // [32][128][2048]
             unsigned short* __restrict__ ao)          // [4096,2048]
{
    __shared__ __align__(16) unsigned short Ks[2][6 * 64 * 32];  // 48 KB dbuf
    __shared__ __align__(16) unsigned short Pl[4][32 * 72];      // 18 KB per-wave P (stride 72)

    const int lb = blockIdx.x;
    const int half = lb >> 8;
    const int qt = half ? 15 - ((lb & 255) >> 5) : ((lb & 255) >> 5);
    const int bh = lb & 31;
    const int b = bh >> 4, h = bh & 15;
    const int tid = threadIdx.x, wave = tid >> 6, lane = tid & 63;
    const int lrow = lane & 15, quad = lane >> 4;
    const int srow = lane >> 2, spiece = lane & 3;
    const int tok0 = b * 2048 + qt * 128;
    unsigned short* Pw = Pl[wave];

    // Q fragments (B-operand layout: n=lane&15=qrow, k=quad*8+j)
    short8 qf[2][6];
#pragma unroll
    for (int mi = 0; mi < 2; mi++) {
        const unsigned short* qp =
            q + (size_t)(tok0 + wave * 32 + mi * 16 + lrow) * 3072 + h * 192;
#pragma unroll
        for (int ks = 0; ks < 6; ks++) qf[mi][ks] = *(const short8*)(qp + ks * 32 + quad * 8);
    }

    float m_st[2], l_st[2];
#pragma unroll
    for (int i = 0; i < 2; i++) {
        m_st[i] = -__builtin_inff();
        l_st[i] = 0.f;
    }
    float4v z4 = {0.f, 0.f, 0.f, 0.f};
    float4v o[2][8];
#pragma unroll
    for (int mi = 0; mi < 2; mi++)
#pragma unroll
        for (int dt = 0; dt < 8; dt++) o[mi][dt] = z4;

    const float scale = 0.07216878364870323f;  // 192^-0.5
    const int nk = 2 * qt + 2;

    auto stageK = [&](int kt, int buf) {
        const int kb = kt * 64;
#pragma unroll
        for (int ii = 0; ii < 6; ++ii) {
            int id = wave * 6 + ii;
            int ks = id >> 2;
            int row = (id & 3) * 16 + srow;
            int key = b * 2048 + kb + row;
            const unsigned short* g =
                (ks < 4) ? kv + (size_t)key * 4096 + h * 256 + ks * 32 + spiece * 8
                         : ckv + (size_t)key * 576 + 512 + (ks - 4) * 32 + spiece * 8;
            async16(&Ks[buf][id * 512], g);
        }
    };

    stageK(0, 0);

    for (int kt = 0; kt < nk; ++kt) {
        __syncthreads();  // drains this wave's DMA; all waves past => buf[kt&1] ready
        if (kt + 1 < nk) stageK(kt + 1, (kt + 1) & 1);  // latency hidden behind compute
        const unsigned short* Kb = Ks[kt & 1];
        const int kb = kt * 64;

        // ---- S^T = K·Q^T : rows=keys, cols=qrows ----
        float4v sc[2][4];
#pragma unroll
        for (int mi = 0; mi < 2; mi++)
#pragma unroll
            for (int nt = 0; nt < 4; nt++) sc[mi][nt] = z4;
#pragma unroll
        for (int ks = 0; ks < 6; ks++) {
#pragma unroll
            for (int nt = 0; nt < 4; nt++) {
                short8 kf = *(const short8*)&Kb[ks * 2048 + (nt * 16 + lrow) * 32 + quad * 8];
                sc[0][nt] = __builtin_amdgcn_mfma_f32_16x16x32_bf16(kf, qf[0][ks], sc[0][nt], 0, 0, 0);
                sc[1][nt] = __builtin_amdgcn_mfma_f32_16x16x32_bf16(kf, qf[1][ks], sc[1][nt], 0, 0, 0);
            }
        }

        // ---- scale + causal mask (S^T: key=kb+nt*16+quad*4+r, qrow=...+lrow) ----
        if (kt >= nk - 2) {
#pragma unroll
            for (int mi = 0; mi < 2; mi++) {
                int rowc = qt * 128 + wave * 32 + mi * 16 + lrow;
#pragma unroll
                for (int nt = 0; nt < 4; nt++)
#pragma unroll
                    for (int r = 0; r < 4; r++) {
                        int keyc = kb + nt * 16 + quad * 4 + r;
                        sc[mi][nt][r] = (keyc > rowc) ? -__builtin_inff()
                                                      : sc[mi][nt][r] * scale;
                    }
            }
        } else {
#pragma unroll
            for (int mi = 0; mi < 2; mi++)
#pragma unroll
                for (int nt = 0; nt < 4; nt++)
#pragma unroll
                    for (int r = 0; r < 4; r++) sc[mi][nt][r] *= scale;
        }

        // ---- online softmax: per-lane row (qrow = lane&15 within mi-half) ----
        float alpha[2];
#pragma unroll
        for (int mi = 0; mi < 2; mi++) {
            float mx = sc[mi][0][0];
#pragma unroll
            for (int nt = 0; nt < 4; nt++)
#pragma unroll
                for (int r = 0; r < 4; r++) mx = fmaxf(mx, sc[mi][nt][r]);
            mx = fmaxf(mx, __shfl_xor(mx, 16));
            mx = fmaxf(mx, __shfl_xor(mx, 32));
            float mnew = fmaxf(m_st[mi], mx);
            float a = __expf(m_st[mi] - mnew);
            m_st[mi] = mnew;
            float rs = 0.f;
#pragma unroll
            for (int nt = 0; nt < 4; nt++) {
                float p0 = __expf(sc[mi][nt][0] - mnew);
                float p1 = __expf(sc[mi][nt][1] - mnew);
                float p2 = __expf(sc[mi][nt][2] - mnew);
                float p3 = __expf(sc[mi][nt][3] - mnew);
                rs += p0 + p1 + p2 + p3;
                uint2v pk;
                pk.x = (unsigned int)f2b(p0) | ((unsigned int)f2b(p1) << 16);
                pk.y = (unsigned int)f2b(p2) | ((unsigned int)f2b(p3) << 16);
                *(uint2v*)&Pw[(mi * 16 + lrow) * 72 + nt * 16 + quad * 4] = pk;
            }
            rs += __shfl_xor(rs, 16);
            rs += __shfl_xor(rs, 32);
            l_st[mi] = l_st[mi] * a + rs;
            alpha[mi] = a;
        }

        // ---- redistribute alpha to O's C-layout rows, rescale O ----
        float arow[2][4];
#pragma unroll
        for (int mi = 0; mi < 2; mi++)
#pragma unroll
            for (int r = 0; r < 4; r++) arow[mi][r] = __shfl(alpha[mi], quad * 4 + r);
#pragma unroll
        for (int mi = 0; mi < 2; mi++)
#pragma unroll
            for (int dt = 0; dt < 8; dt++)
#pragma unroll
                for (int r = 0; r < 4; r++) o[mi][dt][r] *= arow[mi][r];

        // ---- O += P @ V : A=P rows (b128 LDS), B=V^T (b128 global, L2) ----
#pragma unroll
        for (int ks2 = 0; ks2 < 2; ks2++) {
            short8 pa0 = *(const short8*)&Pw[lrow * 72 + ks2 * 32 + quad * 8];
            short8 pa1 = *(const short8*)&Pw[(16 + lrow) * 72 + ks2 * 32 + quad * 8];
#pragma unroll
            for (int dt = 0; dt < 8; dt++) {
                short8 vf = *(const short8*)(vt + ((size_t)bh * 128 + dt * 16 + lrow) * 2048 +
                                             kb + ks2 * 32 + quad * 8);
                o[0][dt] = __builtin_amdgcn_mfma_f32_16x16x32_bf16(pa0, vf, o[0][dt], 0, 0, 0);
                o[1][dt] = __builtin_amdgcn_mfma_f32_16x16x32_bf16(pa1, vf, o[1][dt], 0, 0, 0);
            }
        }
    }

    // ---- finalize: O /= l (redistribute l to C-layout rows), store ----
#pragma unroll
    for (int mi = 0; mi < 2; mi++) {
        float linv_own = 1.f / l_st[mi];
#pragma unroll
        for (int r = 0; r < 4; r++) {
            float linv = __shfl(linv_own, quad * 4 + r);
            unsigned short* dst =
                ao + (size_t)(tok0 + wave * 32 + mi * 16 + quad * 4 + r) * 2048 + h * 128;
#pragma unroll
            for (int dt = 0; dt < 8; dt++) dst[dt * 16 + lrow] = f2b(o[mi][dt][r] * linv);
        }
    }
}

extern "C" void kernel_launch(void* const* d_in, const int* in_sizes, int n_in,
                              void* d_out, int out_size, void* d_ws, size_t ws_size,
                              hipStream_t stream) {
    (void)in_sizes; (void)n_in; (void)out_size; (void)ws_size;
    const float* hs    = (const float*)d_in[0];
    const float* w_qa  = (const float*)d_in[1];
    const float* g_qa  = (const float*)d_in[2];
    const float* w_qb  = (const float*)d_in[3];
    const float* w_kva = (const float*)d_in[4];
    const float* g_kva = (const float*)d_in[5];
    const float* w_kvb = (const float*)d_in[6];
    const float* w_o   = (const float*)d_in[7];

    char* ws = (char*)d_ws;
    size_t off = 0;
    auto alloc = [&](size_t bytes) -> unsigned short* {
        unsigned short* p = (unsigned short*)(ws + off);
        off += (bytes + 255) & ~(size_t)255;
        return p;
    };
    unsigned short* hb    = alloc(4096ull * 2048 * 2);
    unsigned short* wqa   = alloc(1536ull * 2048 * 2);
    unsigned short* wqb   = alloc(3072ull * 1536 * 2);
    unsigned short* wkva  = alloc(576ull * 2048 * 2);
    unsigned short* wkvb  = alloc(4096ull * 512 * 2);
    unsigned short* wo    = alloc(2048ull * 2048 * 2);
    unsigned short* qa    = alloc(4096ull * 1536 * 2);
    unsigned short* ckv   = alloc(4096ull * 576 * 2);
    unsigned short* qbuf  = alloc(4096ull * 3072 * 2);
    unsigned short* kvbuf = alloc(4096ull * 4096 * 2);
    unsigned short* vtb   = alloc(32ull * 128 * 2048 * 2);
    unsigned short* ao    = alloc(4096ull * 2048 * 2);

    auto cvt = [&](const float* src, unsigned short* dst, int n) {
        k_f2b<<<dim3((n / 4 + 255) / 256), dim3(256), 0, stream>>>(src, dst, n);
    };
    cvt(hs, hb, 4096 * 2048);
    cvt(w_qa, wqa, 1536 * 2048);
    cvt(w_qb, wqb, 3072 * 1536);
    cvt(w_kva, wkva, 576 * 2048);
    cvt(w_kvb, wkvb, 4096 * 512);
    cvt(w_o, wo, 2048 * 2048);

    k_gemm_bt<<<dim3(12, 32), 256, 0, stream>>>(hb, 2048, wqa, qa, 1536, 1536, 2048, 0);
    k_gemm_bt<<<dim3(5, 32), 256, 0, stream>>>(hb, 2048, wkva, ckv, 576, 576, 2048, 0);
    k_rmsnorm8<<<dim3(4096), dim3(192), 0, stream>>>(qa, g_qa, 1536, 1536);
    k_rmsnorm8<<<dim3(4096), dim3(64), 0, stream>>>(ckv, g_kva, 576, 512);
    k_rope_k<<<dim3(512), 256, 0, stream>>>(ckv);
    k_gemm_bt<<<dim3(24, 32), 256, 0, stream>>>(qa, 1536, wqb, qbuf, 3072, 3072, 1536, 0);
    k_rope_q<<<dim3(8192), 256, 0, stream>>>(qbuf);
    k_gemm_bt<<<dim3(32, 32), 256, 0, stream>>>(ckv, 576, wkvb, kvbuf, 4096, 4096, 512, 0);
    k_transpose_v<<<dim3(64, 4, 32), 256, 0, stream>>>(kvbuf, vtb);
    k_attn3<<<dim3(512), 256, 0, stream>>>(qbuf, kvbuf, ckv, vtb, ao);
    k_gemm_bt<<<dim3(16, 32), 256, 0, stream>>>(ao, 2048, wo, d_out, 2048, 2048, 2048, 1);
}

// Round 7
// 493.190 us; speedup vs baseline: 1.2197x; 1.2197x over previous
//
#include <hip/hip_runtime.h>
#include <cstdint>
#include <cstring>

typedef short short8 __attribute__((ext_vector_type(8)));
typedef float float4v __attribute__((ext_vector_type(4)));
typedef float float4g __attribute__((ext_vector_type(4)));
typedef unsigned short ushort4v __attribute__((ext_vector_type(4)));
typedef unsigned int uint2v __attribute__((ext_vector_type(2)));

typedef __attribute__((address_space(3))) unsigned int lds_uint;
typedef __attribute__((address_space(1))) const unsigned int glob_uint;

static __device__ __forceinline__ void async16(void* lds, const void* g) {
    __builtin_amdgcn_global_load_lds((glob_uint*)g, (lds_uint*)lds, 16, 0, 0);
}

static __device__ __forceinline__ float b2f(unsigned short u) {
    unsigned int x = ((unsigned int)u) << 16;
    float f;
    __builtin_memcpy(&f, &x, 4);
    return f;
}
static __device__ __forceinline__ unsigned short f2b(float f) {
    unsigned int x;
    __builtin_memcpy(&x, &f, 4);
    unsigned int r = (x + 0x7fffu + ((x >> 16) & 1u)) >> 16;
    return (unsigned short)r;
}

// ---------------- fp32 -> bf16 convert (with optional scale fold) ----------------
__global__ __launch_bounds__(256) void k_f2b(const float* __restrict__ in,
                                             unsigned short* __restrict__ out, int n, float s) {
    int i = (blockIdx.x * 256 + threadIdx.x) * 4;
    if (i >= n) return;
    float4g v = *(const float4g*)(in + i);
    ushort4v r;
    r.x = f2b(v.x * s); r.y = f2b(v.y * s); r.z = f2b(v.z * s); r.w = f2b(v.w * s);
    *(ushort4v*)(out + i) = r;
}

// ---------------- bf16 GEMM (m97 recipe): C[M,N] = A[M,K] @ W[N,K]^T ----------------
__global__ __launch_bounds__(256, 3)
void k_gemm_bt(const unsigned short* __restrict__ A, int lda,
               const unsigned short* __restrict__ W,
               void* __restrict__ C, int ldc,
               int N, int K, int c_fp32) {
    __shared__ __align__(16) unsigned short As[128 * 32];
    __shared__ __align__(16) unsigned short Ws[128 * 32];
    const int tid = threadIdx.x;
    const int m0 = blockIdx.y * 128, n0 = blockIdx.x * 128;
    const int wave = tid >> 6, lane = tid & 63;
    const int wm = (wave >> 1) * 64, wn = (wave & 1) * 64;
    const int lrow = lane & 15, quad = lane >> 4;
    const int srow = lane >> 2, spiece = lane & 3;

    float4v acc[4][4];
    float4v z = {0.f, 0.f, 0.f, 0.f};
#pragma unroll
    for (int i = 0; i < 4; i++)
#pragma unroll
        for (int j = 0; j < 4; j++) acc[i][j] = z;

    for (int k0 = 0; k0 < K; k0 += 32) {
#pragma unroll
        for (int ii = 0; ii < 2; ++ii) {
            int i = wave + ii * 4;
            int row = i * 16 + srow;
            async16(&As[i * 512], &A[(size_t)(m0 + row) * lda + k0 + spiece * 8]);
            int wr = n0 + row;
            if (wr > N - 1) wr = N - 1;
            async16(&Ws[i * 512], &W[(size_t)wr * K + k0 + spiece * 8]);
        }
        __syncthreads();
        short8 af[4], bfr[4];
#pragma unroll
        for (int i = 0; i < 4; i++)
            af[i] = *(const short8*)&As[(wm + i * 16 + lrow) * 32 + quad * 8];
#pragma unroll
        for (int i = 0; i < 4; i++)
            bfr[i] = *(const short8*)&Ws[(wn + i * 16 + lrow) * 32 + quad * 8];
#pragma unroll
        for (int i = 0; i < 4; i++)
#pragma unroll
            for (int j = 0; j < 4; j++)
                acc[i][j] = __builtin_amdgcn_mfma_f32_16x16x32_bf16(af[i], bfr[j], acc[i][j], 0, 0, 0);
        __syncthreads();
    }

    const int rbase = quad * 4;
#pragma unroll
    for (int i = 0; i < 4; i++) {
#pragma unroll
        for (int j = 0; j < 4; j++) {
            int col = n0 + wn + j * 16 + lrow;
            if (col >= N) continue;
#pragma unroll
            for (int r = 0; r < 4; r++) {
                int row = m0 + wm + i * 16 + rbase + r;
                float v = acc[i][j][r];
                if (c_fp32)
                    ((float*)C)[(size_t)row * ldc + col] = v;
                else
                    ((unsigned short*)C)[(size_t)row * ldc + col] = f2b(v);
            }
        }
    }
}

// ---------------- RMSNorm (vectorized short8, one row per block) ----------------
__global__ void k_rmsnorm8(unsigned short* __restrict__ x, const float* __restrict__ g,
                           int ld, int n) {
    int row = blockIdx.x;
    int tid = threadIdx.x;
    size_t base = (size_t)row * ld + tid * 8;
    short8 v8 = *(const short8*)(x + base);
    float vf[8];
    float ss = 0.f;
#pragma unroll
    for (int i = 0; i < 8; i++) {
        vf[i] = b2f((unsigned short)v8[i]);
        ss += vf[i] * vf[i];
    }
    for (int off = 32; off > 0; off >>= 1) ss += __shfl_xor(ss, off);
    __shared__ float wsum[4];
    int nw = blockDim.x >> 6;
    if (nw > 1) {
        int wave = tid >> 6, lane = tid & 63;
        if (lane == 0) wsum[wave] = ss;
        __syncthreads();
        ss = 0.f;
        for (int w = 0; w < nw; w++) ss += wsum[w];
    }
    float scale = rsqrtf(ss / (float)n + 1e-6f);
    short8 r8;
#pragma unroll
    for (int i = 0; i < 8; i++) r8[i] = (short)f2b(vf[i] * scale * g[tid * 8 + i]);
    *(short8*)(x + base) = r8;
}

// ---------------- RoPE on q_pe ----------------
__global__ __launch_bounds__(256) void k_rope_q(unsigned short* __restrict__ q) {
    int idx = blockIdx.x * 256 + threadIdx.x;  // 4096*16*32
    int d = idx & 31;
    int h = (idx >> 5) & 15;
    int t = idx >> 9;
    int s = t & 2047;
    size_t base = (size_t)t * 3072 + h * 192 + 128;
    float inv = powf(10000.0f, -(float)(2 * d) * (1.0f / 64.0f));
    float f = (float)s * inv;
    float c = cosf(f), sn = sinf(f);
    float x1 = b2f(q[base + d]), x2 = b2f(q[base + d + 32]);
    q[base + d] = f2b(x1 * c - x2 * sn);
    q[base + d + 32] = f2b(x2 * c + x1 * sn);
}

// ---------------- RoPE on k_pe ----------------
__global__ __launch_bounds__(256) void k_rope_k(unsigned short* __restrict__ ckv) {
    int idx = blockIdx.x * 256 + threadIdx.x;  // 4096*32
    int d = idx & 31;
    int t = idx >> 5;
    int s = t & 2047;
    size_t base = (size_t)t * 576 + 512;
    float inv = powf(10000.0f, -(float)(2 * d) * (1.0f / 64.0f));
    float f = (float)s * inv;
    float c = cosf(f), sn = sinf(f);
    float x1 = b2f(ckv[base + d]), x2 = b2f(ckv[base + d + 32]);
    ckv[base + d] = f2b(x1 * c - x2 * sn);
    ckv[base + d + 32] = f2b(x2 * c + x1 * sn);
}

// ---------------- V transpose: vt[bh][d][s] ----------------
__global__ __launch_bounds__(256) void k_transpose_v(const unsigned short* __restrict__ kv,
                                                     unsigned short* __restrict__ vt) {
    int bh = blockIdx.z;
    int b = bh >> 4, h = bh & 15;
    int s0 = blockIdx.x * 32, d0 = blockIdx.y * 32;
    __shared__ unsigned short t[32][33];
    int tx = threadIdx.x & 31, ty = threadIdx.x >> 5;
#pragma unroll
    for (int i = 0; i < 4; i++) {
        int s = s0 + ty + i * 8;
        t[ty + i * 8][tx] = kv[(size_t)(b * 2048 + s) * 4096 + h * 256 + 128 + d0 + tx];
    }
    __syncthreads();
#pragma unroll
    for (int i = 0; i < 4; i++) {
        int d = d0 + ty + i * 8;
        vt[((size_t)bh * 128 + d) * 2048 + s0 + tx] = t[tx][ty + i * 8];
    }
}

// ---------------- Flash attention v6 ----------------
// = attn5 with the Ks size bug fixed: each K buffer is 6 ks-chunks x 64 keys x 32
// = 12288 shorts (24KB), NOT 6144. (attn4/5 halved it; stageK buf1 overflowed
// into Vs -> deterministic garbage, barrier-insensitive. attn2/3 had it right.)
__global__ __launch_bounds__(256, 2)
void k_attn6(const unsigned short* __restrict__ q,     // [4096,3072] roped+prescaled
             const unsigned short* __restrict__ kv,    // [4096,4096] k_nope|v
             const unsigned short* __restrict__ ckv,   // [4096,576] cols 512.. roped k_pe
             const unsigned short* __restrict__ vt,    // [32][128][2048]
             unsigned short* __restrict__ ao)          // [4096,2048]
{
    __shared__ __align__(16) unsigned short Ks[2][12288];  // 2 x 24KB dbuf, [ks][64][32]
    __shared__ __align__(16) unsigned short Vs[8192];      // 16KB, [ks2][128][32]
    __shared__ __align__(16) unsigned short Pl[4][1280];   // per-wave P half, 32 rows x 40

    const int lb = blockIdx.x;
    const int qt = (lb < 256) ? (lb >> 5) : 15 - ((lb & 255) >> 5);
    const int bh = lb & 31;
    const int b = bh >> 4, h = bh & 15;
    const int tid = threadIdx.x, wave = tid >> 6, lane = tid & 63;
    const int lrow = lane & 15, quad = lane >> 4;
    const int srow = lane >> 2, spiece = lane & 3;
    const int tok0 = b * 2048 + qt * 128;
    unsigned short* Pw = Pl[wave];

    // Q fragments (B-operand: n=lane&15=qrow, k=quad*8+j); already scaled
    short8 qf[2][6];
#pragma unroll
    for (int mi = 0; mi < 2; mi++) {
        const unsigned short* qp =
            q + (size_t)(tok0 + wave * 32 + mi * 16 + lrow) * 3072 + h * 192;
#pragma unroll
        for (int ks = 0; ks < 6; ks++) qf[mi][ks] = *(const short8*)(qp + ks * 32 + quad * 8);
    }

    short8 ones;
#pragma unroll
    for (int j = 0; j < 8; j++) ones[j] = (short)0x3F80;  // bf16 1.0

    float m_st[2];
    m_st[0] = m_st[1] = -__builtin_inff();
    float4v z4 = {0.f, 0.f, 0.f, 0.f};
    float4v o[2][8], osum[2];
#pragma unroll
    for (int mi = 0; mi < 2; mi++) {
        osum[mi] = z4;
#pragma unroll
        for (int dt = 0; dt < 8; dt++) o[mi][dt] = z4;
    }

    const int nk = 2 * qt + 2;

    auto stageK = [&](int kt, int buf) {
        const int kb = kt * 64;
#pragma unroll
        for (int ii = 0; ii < 6; ++ii) {
            int id = wave * 6 + ii;
            int ks = id >> 2;
            int row = (id & 3) * 16 + srow;
            int key = b * 2048 + kb + row;
            const unsigned short* g =
                (ks < 4) ? kv + (size_t)key * 4096 + h * 256 + ks * 32 + spiece * 8
                         : ckv + (size_t)key * 576 + 512 + (ks - 4) * 32 + spiece * 8;
            async16(&Ks[buf][id * 512], g);
        }
    };
    auto stageV = [&](int kt) {
        const int kb = kt * 64;
#pragma unroll
        for (int ii = 0; ii < 4; ++ii) {
            int id = wave * 4 + ii;
            int d = (id & 7) * 16 + srow;
            const unsigned short* g =
                vt + ((size_t)bh * 128 + d) * 2048 + kb + (id >> 3) * 32 + spiece * 8;
            async16(&Vs[id * 512], g);
        }
    };

    stageK(0, 0);

    for (int kt = 0; kt < nk; ++kt) {
        __syncthreads();  // K(kt) ready; Vs safe to overwrite (prev PV done)
        stageV(kt);                       // consumed after mid barrier
        if (kt + 1 < nk) stageK(kt + 1, (kt + 1) & 1);
        const unsigned short* Kb = Ks[kt & 1];
        const int kb = kt * 64;

        // ---- S^T = K·Q^T (exp2 domain) ----
        float4v sc[2][4];
#pragma unroll
        for (int mi = 0; mi < 2; mi++)
#pragma unroll
            for (int nt = 0; nt < 4; nt++) sc[mi][nt] = z4;
#pragma unroll
        for (int ks = 0; ks < 6; ks++) {
#pragma unroll
            for (int nt = 0; nt < 4; nt++) {
                short8 kf = *(const short8*)&Kb[ks * 2048 + (nt * 16 + lrow) * 32 + quad * 8];
                sc[0][nt] = __builtin_amdgcn_mfma_f32_16x16x32_bf16(kf, qf[0][ks], sc[0][nt], 0, 0, 0);
                sc[1][nt] = __builtin_amdgcn_mfma_f32_16x16x32_bf16(kf, qf[1][ks], sc[1][nt], 0, 0, 0);
            }
        }

        // ---- causal mask (diagonal 128 only) ----
        if (kt >= nk - 2) {
#pragma unroll
            for (int mi = 0; mi < 2; mi++) {
                int rowc = qt * 128 + wave * 32 + mi * 16 + lrow;
#pragma unroll
                for (int nt = 0; nt < 4; nt++)
#pragma unroll
                    for (int r = 0; r < 4; r++) {
                        int keyc = kb + nt * 16 + quad * 4 + r;
                        if (keyc > rowc) sc[mi][nt][r] = -__builtin_inff();
                    }
            }
        }

        // ---- online softmax (max only; sum via ones-column MFMA) ----
        float alpha[2];
        uint2v pk[2][4];
#pragma unroll
        for (int mi = 0; mi < 2; mi++) {
            float mx = sc[mi][0][0];
#pragma unroll
            for (int nt = 0; nt < 4; nt++)
#pragma unroll
                for (int r = 0; r < 4; r++) mx = fmaxf(mx, sc[mi][nt][r]);
            mx = fmaxf(mx, __shfl_xor(mx, 16));
            mx = fmaxf(mx, __shfl_xor(mx, 32));
            float mnew = fmaxf(m_st[mi], mx);
            alpha[mi] = exp2f(m_st[mi] - mnew);
            m_st[mi] = mnew;
#pragma unroll
            for (int nt = 0; nt < 4; nt++) {
                float p0 = exp2f(sc[mi][nt][0] - mnew);
                float p1 = exp2f(sc[mi][nt][1] - mnew);
                float p2 = exp2f(sc[mi][nt][2] - mnew);
                float p3 = exp2f(sc[mi][nt][3] - mnew);
                pk[mi][nt].x = (unsigned int)f2b(p0) | ((unsigned int)f2b(p1) << 16);
                pk[mi][nt].y = (unsigned int)f2b(p2) | ((unsigned int)f2b(p3) << 16);
            }
        }

        // ---- redistribute alpha to O rows, rescale O and osum ----
        float arow[2][4];
#pragma unroll
        for (int mi = 0; mi < 2; mi++)
#pragma unroll
            for (int r = 0; r < 4; r++) arow[mi][r] = __shfl(alpha[mi], quad * 4 + r);
#pragma unroll
        for (int mi = 0; mi < 2; mi++) {
#pragma unroll
            for (int r = 0; r < 4; r++) osum[mi][r] *= arow[mi][r];
#pragma unroll
            for (int dt = 0; dt < 8; dt++)
#pragma unroll
                for (int r = 0; r < 4; r++) o[mi][dt][r] *= arow[mi][r];
        }

        __syncthreads();  // V(kt) DMA complete (cross-wave) — overlapped w/ QK+softmax

        // ---- PV in two 32-key halves through the per-wave P buffer ----
#pragma unroll
        for (int ks2 = 0; ks2 < 2; ks2++) {
#pragma unroll
            for (int mi = 0; mi < 2; mi++) {
                int row = mi * 16 + lrow;
                *(uint2v*)&Pw[row * 40 + quad * 4] = pk[mi][ks2 * 2];
                *(uint2v*)&Pw[row * 40 + 16 + quad * 4] = pk[mi][ks2 * 2 + 1];
            }
            short8 pa0 = *(const short8*)&Pw[lrow * 40 + quad * 8];
            short8 pa1 = *(const short8*)&Pw[(16 + lrow) * 40 + quad * 8];
#pragma unroll
            for (int dt = 0; dt < 8; dt++) {
                short8 vf = *(const short8*)&Vs[(ks2 * 8 + dt) * 512 + lrow * 32 + quad * 8];
                o[0][dt] = __builtin_amdgcn_mfma_f32_16x16x32_bf16(pa0, vf, o[0][dt], 0, 0, 0);
                o[1][dt] = __builtin_amdgcn_mfma_f32_16x16x32_bf16(pa1, vf, o[1][dt], 0, 0, 0);
            }
            osum[0] = __builtin_amdgcn_mfma_f32_16x16x32_bf16(pa0, ones, osum[0], 0, 0, 0);
            osum[1] = __builtin_amdgcn_mfma_f32_16x16x32_bf16(pa1, ones, osum[1], 0, 0, 0);
        }
    }

    // ---- finalize: O /= l (l per-lane via osum), store ----
#pragma unroll
    for (int mi = 0; mi < 2; mi++) {
#pragma unroll
        for (int r = 0; r < 4; r++) {
            float linv = 1.f / osum[mi][r];
            unsigned short* dst =
                ao + (size_t)(tok0 + wave * 32 + mi * 16 + quad * 4 + r) * 2048 + h * 128;
#pragma unroll
            for (int dt = 0; dt < 8; dt++) dst[dt * 16 + lrow] = f2b(o[mi][dt][r] * linv);
        }
    }
}

extern "C" void kernel_launch(void* const* d_in, const int* in_sizes, int n_in,
                              void* d_out, int out_size, void* d_ws, size_t ws_size,
                              hipStream_t stream) {
    (void)in_sizes; (void)n_in; (void)out_size; (void)ws_size;
    const float* hs    = (const float*)d_in[0];
    const float* w_qa  = (const float*)d_in[1];
    const float* g_qa  = (const float*)d_in[2];
    const float* w_qb  = (const float*)d_in[3];
    const float* w_kva = (const float*)d_in[4];
    const float* g_kva = (const float*)d_in[5];
    const float* w_kvb = (const float*)d_in[6];
    const float* w_o   = (const float*)d_in[7];

    char* ws = (char*)d_ws;
    size_t off = 0;
    auto alloc = [&](size_t bytes) -> unsigned short* {
        unsigned short* p = (unsigned short*)(ws + off);
        off += (bytes + 255) & ~(size_t)255;
        return p;
    };
    unsigned short* hb    = alloc(4096ull * 2048 * 2);
    unsigned short* wqa   = alloc(1536ull * 2048 * 2);
    unsigned short* wqb   = alloc(3072ull * 1536 * 2);
    unsigned short* wkva  = alloc(576ull * 2048 * 2);
    unsigned short* wkvb  = alloc(4096ull * 512 * 2);
    unsigned short* wo    = alloc(2048ull * 2048 * 2);
    unsigned short* qa    = alloc(4096ull * 1536 * 2);
    unsigned short* ckv   = alloc(4096ull * 576 * 2);
    unsigned short* qbuf  = alloc(4096ull * 3072 * 2);
    unsigned short* kvbuf = alloc(4096ull * 4096 * 2);
    unsigned short* vtb   = alloc(32ull * 128 * 2048 * 2);
    unsigned short* ao    = alloc(4096ull * 2048 * 2);

    auto cvt = [&](const float* src, unsigned short* dst, int n, float s) {
        k_f2b<<<dim3((n / 4 + 255) / 256), dim3(256), 0, stream>>>(src, dst, n, s);
    };
    // fold softmax scale * log2(e) into w_qb (RoPE is linear -> commutes)
    const float qscale = 0.07216878364870323f * 1.4426950408889634f;
    cvt(hs, hb, 4096 * 2048, 1.0f);
    cvt(w_qa, wqa, 1536 * 2048, 1.0f);
    cvt(w_qb, wqb, 3072 * 1536, qscale);
    cvt(w_kva, wkva, 576 * 2048, 1.0f);
    cvt(w_kvb, wkvb, 4096 * 512, 1.0f);
    cvt(w_o, wo, 2048 * 2048, 1.0f);

    k_gemm_bt<<<dim3(12, 32), 256, 0, stream>>>(hb, 2048, wqa, qa, 1536, 1536, 2048, 0);
    k_gemm_bt<<<dim3(5, 32), 256, 0, stream>>>(hb, 2048, wkva, ckv, 576, 576, 2048, 0);
    k_rmsnorm8<<<dim3(4096), dim3(192), 0, stream>>>(qa, g_qa, 1536, 1536);
    k_rmsnorm8<<<dim3(4096), dim3(64), 0, stream>>>(ckv, g_kva, 576, 512);
    k_rope_k<<<dim3(512), 256, 0, stream>>>(ckv);
    k_gemm_bt<<<dim3(24, 32), 256, 0, stream>>>(qa, 1536, wqb, qbuf, 3072, 3072, 1536, 0);
    k_rope_q<<<dim3(8192), 256, 0, stream>>>(qbuf);
    k_gemm_bt<<<dim3(32, 32), 256, 0, stream>>>(ckv, 576, wkvb, kvbuf, 4096, 4096, 512, 0);
    k_transpose_v<<<dim3(64, 4, 32), 256, 0, stream>>>(kvbuf, vtb);
    k_attn6<<<dim3(512), 256, 0, stream>>>(qbuf, kvbuf, ckv, vtb, ao);
    k_gemm_bt<<<dim3(16, 32), 256, 0, stream>>>(ao, 2048, wo, d_out, 2048, 2048, 2048, 1);
}